// Round 18
// baseline (486.300 us; speedup 1.0000x reference)
//
#include <hip/hip_runtime.h>
#include <hip/hip_bf16.h>

typedef __bf16 bf16;
typedef __bf16 bf16x4 __attribute__((ext_vector_type(4)));
typedef __bf16 bf16x8 __attribute__((ext_vector_type(8)));
typedef float f32x4 __attribute__((ext_vector_type(4)));

#define MFMA(a, b, c) __builtin_amdgcn_mfma_f32_16x16x32_bf16(a, b, c, 0, 0, 0)

// Q pre-scale: attention scale (64^-0.5 = 0.125) folded with log2(e).
#define QSCALE (0.125f * 1.44269504088896340736f)

// Geometry: b=4, n=2048, dim=256, H=8, D=32
#define OFF_Q  262144
#define OFF_K  (OFF_Q + 2097152)
#define OFF_VT (OFF_K + 2097152)
#define OFF_P  (OFF_VT + 2097152)
#define OFF_L  (OFF_P + 4194304)
#define OFF_BAR (OFF_L + 262144)   // 3 barrier slots (128B apart), memset to 0

static __device__ __forceinline__ float fexp2(float x) {
    return __builtin_amdgcn_exp2f(x);
}

#define GLL16(g, l)                                                              \
    __builtin_amdgcn_global_load_lds(                                            \
        (const __attribute__((address_space(1))) void*)(g),                      \
        (__attribute__((address_space(3))) void*)(l), 16, 0, 0)

// Flat single-use grid barrier: one atomic inc per block, spin on count==nb.
// Slots are zeroed by hipMemsetAsync before each (captured) launch.
static __device__ __forceinline__ void gridbar(unsigned* slot, unsigned nb) {
    __syncthreads();
    __threadfence();   // device-scope release: drain my phase's writes
    if (threadIdx.x == 0) {
        __hip_atomic_fetch_add(slot, 1u, __ATOMIC_ACQ_REL, __HIP_MEMORY_SCOPE_AGENT);
        while (__hip_atomic_load(slot, __ATOMIC_ACQUIRE, __HIP_MEMORY_SCOPE_AGENT) < nb)
            __builtin_amdgcn_s_sleep(2);
    }
    __syncthreads();
    __threadfence();   // device-scope acquire: invalidate stale lines
}

// ======================= device phase helpers (shared) ========================

static __device__ __forceinline__ void wt_unit(int u, const float* Wq,
                                               const float* Wk, const float* Wv,
                                               const float* Wo, bf16* wts,
                                               bf16* smem, int t) {
    bf16(*tile)[64] = reinterpret_cast<bf16(*)[64]>(smem);
    int rb = u & 3, ob = (u >> 2) & 3, mat = u >> 4;
    const float* src = (mat == 0) ? Wq : (mat == 1) ? Wk : (mat == 2) ? Wv : Wo;
    int lr = t >> 4, lc = (t & 15) * 4;
#pragma unroll
    for (int rr = 0; rr < 4; ++rr) {
        int i = rb * 64 + rr * 16 + lr;
        f32x4 a = *reinterpret_cast<const f32x4*>(src + (size_t)i * 256 + ob * 64 + lc);
        bf16x4 v;
#pragma unroll
        for (int j = 0; j < 4; ++j) v[j] = (bf16)a[j];
        *reinterpret_cast<bf16x4*>(&tile[rr * 16 + lr][lc]) = v;
    }
    __syncthreads();
    int ol = t >> 2, ib = (t & 3) * 16;
    int o = ob * 64 + ol;
    bf16x8 v0, v1;
#pragma unroll
    for (int k = 0; k < 8; ++k) {
        v0[k] = tile[ib + k][ol];
        v1[k] = tile[ib + 8 + k][ol];
    }
    bf16* dst = wts + (size_t)mat * 65536 + (size_t)o * 256 + rb * 64 + ib;
    *reinterpret_cast<bf16x8*>(dst) = v0;
    *reinterpret_cast<bf16x8*>(dst + 8) = v1;
}

static __device__ __forceinline__ void proj_unit(int u, const float* c1,
                                                 const float* c2, const bf16* wts,
                                                 bf16* Q, bf16* Vt, bf16* smem,
                                                 int t) {
    int m = u & 255, mat = u >> 8;
    const float* src = (mat == 0) ? c1 : c2;
    const float* base = src + (size_t)m * 32 * 256;
    bf16* sA = smem;   // 16 KB

#pragma unroll
    for (int k = 0; k < 4; ++k) {
        int p = t + 256 * k;
        int rg = p >> 9, kc = (p >> 6) & 7, l = p & 63;
        const float* ap = base + (size_t)(rg * 16 + (l & 15)) * 256 + kc * 32 + (l >> 4) * 8;
        f32x4 a0 = *reinterpret_cast<const f32x4*>(ap);
        f32x4 a1 = *reinterpret_cast<const f32x4*>(ap + 4);
        bf16x8 v;
#pragma unroll
        for (int j = 0; j < 4; ++j) { v[j] = (bf16)a0[j]; v[j + 4] = (bf16)a1[j]; }
        *reinterpret_cast<bf16x8*>(&sA[p * 8]) = v;
    }
    __syncthreads();

    int w = t >> 6, lane = t & 63, cc = lane & 15, g = lane >> 4;
    const bf16* wt = wts + (size_t)mat * 65536;

    f32x4 acc[2][4] = {};
#pragma unroll
    for (int kc = 0; kc < 8; ++kc) {
        bf16x8 af0 = *reinterpret_cast<const bf16x8*>(&sA[(kc * 64 + lane) * 8]);
        bf16x8 af1 = *reinterpret_cast<const bf16x8*>(&sA[(512 + kc * 64 + lane) * 8]);
#pragma unroll
        for (int ct = 0; ct < 4; ++ct) {
            bf16x8 bf = *reinterpret_cast<const bf16x8*>(
                wt + (size_t)(w * 64 + ct * 16 + cc) * 256 + kc * 32 + g * 8);
            if (mat == 2) {
                acc[0][ct] = MFMA(bf, af0, acc[0][ct]);   // D[wcol][row]
                acc[1][ct] = MFMA(bf, af1, acc[1][ct]);
            } else {
                acc[0][ct] = MFMA(af0, bf, acc[0][ct]);
                acc[1][ct] = MFMA(af1, bf, acc[1][ct]);
            }
        }
    }

    if (mat != 2) {
        float os = (mat == 0) ? QSCALE : 1.0f;
        bf16* dst = Q + (size_t)mat * 2097152;   // natural [8192][256]
#pragma unroll
        for (int rg = 0; rg < 2; ++rg)
#pragma unroll
            for (int ct = 0; ct < 4; ++ct) {
                int col = w * 64 + ct * 16 + cc;
#pragma unroll
                for (int j = 0; j < 4; ++j) {
                    int row = m * 32 + rg * 16 + 4 * g + j;
                    dst[(size_t)row * 256 + col] = (bf16)(acc[rg][ct][j] * os);
                }
            }
    } else {
        int n0 = m * 32;
        int b = n0 >> 11, nb = (n0 & 2047) >> 6, nlo = n0 & 63;
        size_t cbase = ((size_t)(b * 32 + nb)) * 256;
#pragma unroll
        for (int rg = 0; rg < 2; ++rg)
#pragma unroll
            for (int ct = 0; ct < 4; ++ct) {
#pragma unroll
                for (int j = 0; j < 4; ++j) {
                    int c = w * 64 + ct * 16 + 4 * g + j;
                    Vt[(cbase + c) * 64 + nlo + rg * 16 + cc] = (bf16)acc[rg][ct][j];
                }
            }
    }
}

static __device__ __forceinline__ void attn_unit(int u, const bf16* Q,
                                                 const bf16* K, const bf16* Vt,
                                                 bf16* P, float* Lf, bf16* sK,
                                                 bf16* sV, int t) {
    int xcd = u & 7;
    int sub = u >> 3;
    int bh = xcd * 4 + (sub & 3);
    int rest = sub >> 2;
    int xtile = rest & 15;
    int split = rest >> 4;

    int b = bh >> 3, hd = bh & 7;
    int kv0 = split << 10;
    int lane = t & 63;
    int w = t >> 6;
    int cc = lane & 15, g = lane >> 4;
    int qrow0 = xtile * 128 + w * 32;

    const bf16* Qh = Q + (size_t)(b * 2048) * 256 + hd * 32;
    size_t kbase0 = (size_t)(b * 2048) * 256 + hd * 32;
    const bf16* Vtb = Vt + (size_t)(b * 32) * 256 * 64;

    bf16x8 qf[2];
#pragma unroll
    for (int h = 0; h < 2; ++h)
        qf[h] = *reinterpret_cast<const bf16x8*>(
            Qh + (size_t)(qrow0 + h * 16 + cc) * 256 + g * 8);

    int kp0 = 8 * (cc >> 2) + (cc & 3);
    int koff[4];
#pragma unroll
    for (int r = 0; r < 4; ++r) {
        int kp = 32 * (r >> 1) + 4 * (r & 1) + kp0;
        int fr = ((kp >> 1) ^ (kp >> 3)) & 3;
        koff[r] = kp * 32 + ((g ^ fr) * 8);
    }

    int krow = w * 16 + (lane >> 2);
    int fkr = ((krow >> 1) ^ (krow >> 3)) & 3;
    int kcol = (((lane & 3) ^ fkr)) * 8;
    int dv = w * 8 + (lane >> 3);
    int vcol = ((lane & 7) ^ (lane >> 3)) * 8;

    float lsum[2] = {0.f, 0.f};
    f32x4 oA[2] = {}, oB[2] = {};

#define STAGE(tt, buf)                                                          \
    do {                                                                        \
        int kb_ = kv0 + (tt) * 64;                                              \
        const bf16* kg_ = K + kbase0 + (size_t)(kb_ + krow) * 256 + kcol;       \
        GLL16(kg_, &sK[(buf) * 2048 + w * 512]);                                \
        const bf16* vg_ = Vtb + ((size_t)(kb_ >> 6) * 256 + hd * 32 + dv) * 64  \
                          + vcol;                                               \
        GLL16(vg_, &sV[(buf) * 2048 + w * 512]);                                \
    } while (0)

    STAGE(0, 0);
    STAGE(1, 1);

    for (int kt = 0; kt < 16; ++kt) {
        int cur = kt & 3;
        if (kt + 2 < 16) {
            STAGE(kt + 2, (kt + 2) & 3);
            asm volatile("s_waitcnt vmcnt(4)" ::: "memory");
        } else {
            asm volatile("s_waitcnt vmcnt(0)" ::: "memory");
        }
        __builtin_amdgcn_s_barrier();
        __builtin_amdgcn_sched_barrier(0);

        bf16x8 kf[4], vf[4];
#pragma unroll
        for (int r = 0; r < 4; ++r)
            kf[r] = *reinterpret_cast<const bf16x8*>(&sK[cur * 2048 + koff[r]]);
#pragma unroll
        for (int dt = 0; dt < 2; ++dt)
#pragma unroll
            for (int kk = 0; kk < 2; ++kk) {
                int colp = (kk * 4 + g) ^ (cc & 7);
                vf[dt * 2 + kk] = *reinterpret_cast<const bf16x8*>(
                    &sV[cur * 2048 + (dt * 16 + cc) * 64 + colp * 8]);
            }

#pragma unroll
        for (int h = 0; h < 2; ++h) {
            f32x4 z = {};
            f32x4 s[4];
            __builtin_amdgcn_s_setprio(1);
#pragma unroll
            for (int r = 0; r < 4; ++r) s[r] = MFMA(kf[r], qf[h], z);
            __builtin_amdgcn_s_setprio(0);

#pragma unroll
            for (int r = 0; r < 4; ++r)
#pragma unroll
                for (int j = 0; j < 4; ++j) s[r][j] = fexp2(s[r][j]);
            float t0 = (s[0][0] + s[0][1]) + (s[0][2] + s[0][3]);
            float t1 = (s[1][0] + s[1][1]) + (s[1][2] + s[1][3]);
            float t2 = (s[2][0] + s[2][1]) + (s[2][2] + s[2][3]);
            float t3 = (s[3][0] + s[3][1]) + (s[3][2] + s[3][3]);
            lsum[h] += (t0 + t1) + (t2 + t3);

            bf16x8 pb[2];
#pragma unroll
            for (int kk = 0; kk < 2; ++kk)
#pragma unroll
                for (int e = 0; e < 8; ++e)
                    pb[kk][e] = (bf16)s[2 * kk + (e >> 2)][e & 3];

            __builtin_amdgcn_s_setprio(1);
            oA[h] = MFMA(vf[0], pb[0], oA[h]);
            oA[h] = MFMA(vf[1], pb[1], oA[h]);
            oB[h] = MFMA(vf[2], pb[0], oB[h]);
            oB[h] = MFMA(vf[3], pb[1], oB[h]);
            __builtin_amdgcn_s_setprio(0);
        }
    }
#undef STAGE

#pragma unroll
    for (int h = 0; h < 2; ++h) {
        lsum[h] += __shfl_xor(lsum[h], 16);
        lsum[h] += __shfl_xor(lsum[h], 32);

        bf16* Pp = P + (size_t)split * 2097152 +
                   ((size_t)b * 2048 + qrow0 + h * 16 + cc) * 256 + hd * 32;
        bf16x4 w0, w1;
#pragma unroll
        for (int j = 0; j < 4; ++j) {
            w0[j] = (bf16)oA[h][j];
            w1[j] = (bf16)oB[h][j];
        }
        *reinterpret_cast<bf16x4*>(Pp + 4 * g) = w0;
        *reinterpret_cast<bf16x4*>(Pp + 16 + 4 * g) = w1;
        if (g == 0)
            Lf[(size_t)split * 65536 + (size_t)bh * 2048 + qrow0 + h * 16 + cc] = lsum[h];
    }
}

static __device__ __forceinline__ void out_unit(int gw, const bf16* P,
                                                const float* Lf, const bf16* WoT,
                                                const float* bo, float* out,
                                                int lane) {
    int m = gw >> 2, nb = gw & 3;
    int cc = lane & 15, g = lane >> 4;
    int arow = m * 16 + cc;
    int b = arow >> 11, n = arow & 2047;

    f32x4 acc[4] = {};
#pragma unroll
    for (int kc = 0; kc < 8; ++kc) {   // kc == head index
        float l0 = Lf[(size_t)(b * 8 + kc) * 2048 + n];
        float l1 = Lf[65536 + (size_t)(b * 8 + kc) * 2048 + n];
        float inv = 1.0f / (l0 + l1);
        bf16x8 p0 = *reinterpret_cast<const bf16x8*>(
            P + (size_t)arow * 256 + kc * 32 + g * 8);
        bf16x8 p1 = *reinterpret_cast<const bf16x8*>(
            P + 2097152 + (size_t)arow * 256 + kc * 32 + g * 8);
        bf16x8 af;
#pragma unroll
        for (int e = 0; e < 8; ++e)
            af[e] = (bf16)(((float)p0[e] + (float)p1[e]) * inv);
#pragma unroll
        for (int ct = 0; ct < 4; ++ct) {
            bf16x8 bf = *reinterpret_cast<const bf16x8*>(
                WoT + (size_t)(nb * 64 + ct * 16 + cc) * 256 + kc * 32 + g * 8);
            acc[ct] = MFMA(af, bf, acc[ct]);
        }
    }
#pragma unroll
    for (int ct = 0; ct < 4; ++ct) {
        int col = nb * 64 + ct * 16 + cc;
        float bias = bo[col];
#pragma unroll
        for (int j = 0; j < 4; ++j) {
            int row = m * 16 + 4 * g + j;
            out[(size_t)row * 256 + col] = acc[ct][j] + bias;
        }
    }
}

// ======================= cooperative mega-kernel ==============================
// Same validated phase logic as round 17; cg::sync replaced by flat atomic
// barrier (3 single-use slots in ws, zeroed by captured hipMemsetAsync).
__global__ __launch_bounds__(256, 4) void k_mega(
    const float* __restrict__ c2, const float* __restrict__ c1,
    const float* __restrict__ Wq, const float* __restrict__ Wk,
    const float* __restrict__ Wv, const float* __restrict__ Wo,
    const float* __restrict__ bo, float* __restrict__ out,
    bf16* __restrict__ ws) {
    __shared__ __align__(16) bf16 smem[16384];   // 32 KB overlay
    const int bid = blockIdx.x;
    const int G = gridDim.x;
    const int t = threadIdx.x;

    bf16* wts = ws;
    bf16* Q = ws + OFF_Q;
    bf16* K = ws + OFF_K;
    bf16* Vt = ws + OFF_VT;
    bf16* P = ws + OFF_P;
    float* Lf = (float*)(ws + OFF_L);
    unsigned* bar = (unsigned*)(ws + OFF_BAR);

    for (int u = bid; u < 64; u += G) {
        wt_unit(u, Wq, Wk, Wv, Wo, wts, smem, t);
        __syncthreads();
    }
    gridbar(bar, (unsigned)G);

    for (int u = bid; u < 768; u += G) {
        proj_unit(u, c1, c2, wts, Q, Vt, smem, t);
        __syncthreads();
    }
    gridbar(bar + 32, (unsigned)G);

    for (int u = bid; u < 1024; u += G)
        attn_unit(u, Q, K, Vt, P, Lf, smem, smem + 8192, t);
    gridbar(bar + 64, (unsigned)G);

    {
        int w4 = t >> 6, lane = t & 63;
        const bf16* WoT = wts + 3 * 65536;
        for (int u = bid; u < 512; u += G)
            out_unit(u * 4 + w4, P, Lf, WoT, bo, out, lane);
    }
}

// ======================= fallback: four separate kernels ======================
__global__ __launch_bounds__(256) void f_wt(const float* __restrict__ Wq,
                                            const float* __restrict__ Wk,
                                            const float* __restrict__ Wv,
                                            const float* __restrict__ Wo,
                                            bf16* __restrict__ wts) {
    __shared__ __align__(16) bf16 smem[4096];
    wt_unit(blockIdx.x, Wq, Wk, Wv, Wo, wts, smem, threadIdx.x);
}

__global__ __launch_bounds__(256) void f_proj(const float* __restrict__ c1,
                                              const float* __restrict__ c2,
                                              const bf16* __restrict__ wts,
                                              bf16* __restrict__ ws) {
    __shared__ __align__(16) bf16 smem[8192];
    proj_unit(blockIdx.x, c1, c2, wts, ws + OFF_Q, ws + OFF_VT, smem,
              threadIdx.x);
}

__global__ __launch_bounds__(256, 4) void f_attn(const bf16* __restrict__ Q,
                                                 const bf16* __restrict__ K,
                                                 const bf16* __restrict__ Vt,
                                                 bf16* __restrict__ P,
                                                 float* __restrict__ Lf) {
    __shared__ __align__(16) bf16 smem[16384];
    attn_unit(blockIdx.x, Q, K, Vt, P, Lf, smem, smem + 8192, threadIdx.x);
}

__global__ __launch_bounds__(256) void f_out(const bf16* __restrict__ P,
                                             const float* __restrict__ Lf,
                                             const bf16* __restrict__ WoT,
                                             const float* __restrict__ bo,
                                             float* __restrict__ out) {
    out_unit(blockIdx.x * 4 + (threadIdx.x >> 6), P, Lf, WoT, bo, out,
             threadIdx.x & 63);
}

extern "C" void kernel_launch(void* const* d_in, const int* in_sizes, int n_in,
                              void* d_out, int out_size, void* d_ws, size_t ws_size,
                              hipStream_t stream) {
    const float* c2 = (const float*)d_in[0];
    const float* c1 = (const float*)d_in[1];
    const float* Wq = (const float*)d_in[2];
    const float* Wk = (const float*)d_in[3];
    const float* Wv = (const float*)d_in[4];
    const float* Wo = (const float*)d_in[5];
    const float* bo = (const float*)d_in[6];
    float* out = (float*)d_out;
    bf16* ws = (bf16*)d_ws;

    // Zero the 3 barrier slots (captured in the graph -> re-zeroed each replay).
    hipMemsetAsync((char*)d_ws + (size_t)OFF_BAR * 2, 0, 384, stream);

    int dev = 0;
    (void)hipGetDevice(&dev);
    int cus = 0;
    (void)hipDeviceGetAttribute(&cus, hipDeviceAttributeMultiprocessorCount, dev);
    int maxb = 0;
    hipError_t eocc = hipOccupancyMaxActiveBlocksPerMultiprocessor(&maxb, k_mega, 256, 0);

    hipError_t err = hipErrorUnknown;
    if (eocc == hipSuccess && maxb > 0 && cus > 0) {
        int grid = maxb * cus;
        if (grid > 1024) grid = 1024;
        if (grid >= 64) {
            void* args[] = {(void*)&c2, (void*)&c1, (void*)&Wq, (void*)&Wk,
                            (void*)&Wv, (void*)&Wo, (void*)&bo, (void*)&out,
                            (void*)&ws};
            err = hipLaunchCooperativeKernel((void*)k_mega, dim3(grid), dim3(256),
                                             args, 0, stream);
        }
    }
    if (err != hipSuccess) {
        // Fallback: known-good four-kernel path (round-14-equivalent, 71 us).
        f_wt<<<dim3(64), 256, 0, stream>>>(Wq, Wk, Wv, Wo, ws);
        f_proj<<<dim3(768), 256, 0, stream>>>(c1, c2, ws, ws);
        f_attn<<<dim3(1024), 256, 0, stream>>>(ws + OFF_Q, ws + OFF_K,
                                               ws + OFF_VT, ws + OFF_P,
                                               (float*)(ws + OFF_L));
        f_out<<<dim3(512), 256, 0, stream>>>(ws + OFF_P, (float*)(ws + OFF_L),
                                             ws + 3 * 65536, bo, out);
    }
}

// Round 19
// 70.659 us; speedup vs baseline: 6.8823x; 6.8823x over previous
//
#include <hip/hip_runtime.h>
#include <hip/hip_bf16.h>

typedef __bf16 bf16;
typedef __bf16 bf16x4 __attribute__((ext_vector_type(4)));
typedef __bf16 bf16x8 __attribute__((ext_vector_type(8)));
typedef float f32x4 __attribute__((ext_vector_type(4)));

#define MFMA(a, b, c) __builtin_amdgcn_mfma_f32_16x16x32_bf16(a, b, c, 0, 0, 0)

// Q pre-scale: attention scale (64^-0.5 = 0.125) folded with log2(e).
#define QSCALE (0.125f * 1.44269504088896340736f)

// Geometry: b=4, n=2048, dim=256, H=8, D=32
// ws layout (bf16 elems):
//   [0)      WqT,WkT,WvT,WoT each 65536 (Wt[out][in])
//   [OFF_Q)  Q  [b][n][256] natural layout (pre-scaled)
//   [OFF_K)  K  [b][n][256] natural layout
//   [OFF_VT) Vt BLOCKED [b][nb=n/64][c=256][64]  (c = h*32+d)
//   [OFF_P)  P partials [split=2][b*n=8192][256] bf16 (unnormalized O)
//   [OFF_L)  L partials [split=2][bh=32][2048] f32 (lsum)
#define OFF_Q  262144
#define OFF_K  (OFF_Q + 2097152)
#define OFF_VT (OFF_K + 2097152)
#define OFF_P  (OFF_VT + 2097152)
#define OFF_L  (OFF_P + 4194304)

static __device__ __forceinline__ float fexp2(float x) {
    return __builtin_amdgcn_exp2f(x);
}

#define GLL16(g, l)                                                              \
    __builtin_amdgcn_global_load_lds(                                            \
        (const __attribute__((address_space(1))) void*)(g),                      \
        (__attribute__((address_space(3))) void*)(l), 16, 0, 0)

// ---------------- kernel 0: weights -> bf16 transposed, via LDS ---------------
__global__ __launch_bounds__(256) void k_wt(const float* __restrict__ Wq,
                                            const float* __restrict__ Wk,
                                            const float* __restrict__ Wv,
                                            const float* __restrict__ Wo,
                                            bf16* __restrict__ wts) {
    __shared__ __align__(16) bf16 tile[64][64];   // [i][o]
    int rb = blockIdx.x, ob = blockIdx.y, mat = blockIdx.z;
    const float* src = (mat == 0) ? Wq : (mat == 1) ? Wk : (mat == 2) ? Wv : Wo;
    int t = threadIdx.x;
    int lr = t >> 4, lc = (t & 15) * 4;
#pragma unroll
    for (int rr = 0; rr < 4; ++rr) {
        int i = rb * 64 + rr * 16 + lr;
        f32x4 a = *reinterpret_cast<const f32x4*>(src + (size_t)i * 256 + ob * 64 + lc);
        bf16x4 v;
#pragma unroll
        for (int j = 0; j < 4; ++j) v[j] = (bf16)a[j];
        *reinterpret_cast<bf16x4*>(&tile[rr * 16 + lr][lc]) = v;
    }
    __syncthreads();
    int ol = t >> 2, ib = (t & 3) * 16;
    int o = ob * 64 + ol;
    bf16x8 v0, v1;
#pragma unroll
    for (int k = 0; k < 8; ++k) {
        v0[k] = tile[ib + k][ol];
        v1[k] = tile[ib + 8 + k][ol];
    }
    bf16* dst = wts + (size_t)mat * 65536 + (size_t)o * 256 + rb * 64 + ib;
    *reinterpret_cast<bf16x8*>(dst) = v0;
    *reinterpret_cast<bf16x8*>(dst + 8) = v1;
}

// ---------------- kernel 1: q/k/v projections, v2 -----------------------------
// grid (256, 3): x = 32-row strip, y = mat. block 256 = 4 waves.
// A-strip staged to LDS in MFMA-fragment order [rg][kc][lane*8] with a
// thread->position map giving contiguous 16B LDS writes (zero conflicts).
// Wave w computes cols [w*64,(w+1)*64), both 16-row groups.
// mat 2 uses swapped MFMA -> Vt, stored BLOCKED [b][nb][c][64]: the strip's
// 32-n window is exactly one 64B line per c-row, owned by this block alone.
__global__ __launch_bounds__(256) void k_proj(const float* __restrict__ c1,
                                              const float* __restrict__ c2,
                                              const bf16* __restrict__ wts,
                                              bf16* __restrict__ qkv) {
    __shared__ __align__(16) bf16 sA[1024 * 8];   // [rg2][kc8][l64]*8 = 16KB
    int m = blockIdx.x, mat = blockIdx.y;
    const float* src = (mat == 0) ? c1 : c2;
    int t = threadIdx.x;
    const float* base = src + (size_t)m * 32 * 256;

#pragma unroll
    for (int k = 0; k < 4; ++k) {
        int p = t + 256 * k;             // 0..1023
        int rg = p >> 9, kc = (p >> 6) & 7, l = p & 63;
        const float* ap = base + (size_t)(rg * 16 + (l & 15)) * 256 + kc * 32 + (l >> 4) * 8;
        f32x4 a0 = *reinterpret_cast<const f32x4*>(ap);
        f32x4 a1 = *reinterpret_cast<const f32x4*>(ap + 4);
        bf16x8 v;
#pragma unroll
        for (int j = 0; j < 4; ++j) { v[j] = (bf16)a0[j]; v[j + 4] = (bf16)a1[j]; }
        *reinterpret_cast<bf16x8*>(&sA[p * 8]) = v;   // byte p*16: contiguous
    }
    __syncthreads();

    int w = t >> 6, lane = t & 63, cc = lane & 15, g = lane >> 4;
    const bf16* wt = wts + (size_t)mat * 65536;

    f32x4 acc[2][4] = {};
#pragma unroll
    for (int kc = 0; kc < 8; ++kc) {
        bf16x8 af0 = *reinterpret_cast<const bf16x8*>(&sA[(kc * 64 + lane) * 8]);
        bf16x8 af1 = *reinterpret_cast<const bf16x8*>(&sA[(512 + kc * 64 + lane) * 8]);
#pragma unroll
        for (int ct = 0; ct < 4; ++ct) {
            bf16x8 bf = *reinterpret_cast<const bf16x8*>(
                wt + (size_t)(w * 64 + ct * 16 + cc) * 256 + kc * 32 + g * 8);
            if (mat == 2) {
                acc[0][ct] = MFMA(bf, af0, acc[0][ct]);   // D[wcol][row]
                acc[1][ct] = MFMA(bf, af1, acc[1][ct]);
            } else {
                acc[0][ct] = MFMA(af0, bf, acc[0][ct]);
                acc[1][ct] = MFMA(af1, bf, acc[1][ct]);
            }
        }
    }

    if (mat != 2) {
        float os = (mat == 0) ? QSCALE : 1.0f;
        bf16* dst = qkv + (size_t)mat * 2097152;   // natural [8192][256]
#pragma unroll
        for (int rg = 0; rg < 2; ++rg)
#pragma unroll
            for (int ct = 0; ct < 4; ++ct) {
                int col = w * 64 + ct * 16 + cc;
#pragma unroll
                for (int j = 0; j < 4; ++j) {
                    int row = m * 32 + rg * 16 + 4 * g + j;
                    dst[(size_t)row * 256 + col] = (bf16)(acc[rg][ct][j] * os);
                }
            }
    } else {
        bf16* vt = qkv + (size_t)2 * 2097152;      // Vt blocked [b][nb][c][64]
        int n0 = m * 32;
        int b = n0 >> 11, nb = (n0 & 2047) >> 6, nlo = n0 & 63;   // nlo in {0,32}
        size_t cbase = ((size_t)(b * 32 + nb)) * 256;
#pragma unroll
        for (int rg = 0; rg < 2; ++rg)
#pragma unroll
            for (int ct = 0; ct < 4; ++ct) {
#pragma unroll
                for (int j = 0; j < 4; ++j) {
                    int c = w * 64 + ct * 16 + 4 * g + j;
                    vt[(cbase + c) * 64 + nlo + rg * 16 + cc] = (bf16)acc[rg][ct][j];
                }
            }
    }
}

// ---------------- kernel 2: flash attention, counted-vmcnt + K chunk-swizzle --
// Round-10 pipeline; V staging SOURCE address uses the blocked Vt layout
// (per-lane gather; sV content/LDS layout unchanged).
__global__ __launch_bounds__(256, 4) void k_attn(const bf16* __restrict__ Q,
                                                 const bf16* __restrict__ K,
                                                 const bf16* __restrict__ Vt,
                                                 bf16* __restrict__ P,
                                                 float* __restrict__ Lf) {
    __shared__ __align__(16) bf16 sK[4][2048];   // [buf][64 kv-rows * 32 d] swz
    __shared__ __align__(16) bf16 sV[4][2048];   // [buf][32 d * 64 kv] swz

    int flat = blockIdx.x;
    int xcd = flat & 7;
    int sub = flat >> 3;
    int bh = xcd * 4 + (sub & 3);
    int rest = sub >> 2;
    int xtile = rest & 15;
    int split = rest >> 4;

    int b = bh >> 3, hd = bh & 7;
    int kv0 = split << 10;
    int lane = threadIdx.x & 63;
    int w = threadIdx.x >> 6;
    int cc = lane & 15, g = lane >> 4;
    int qrow0 = xtile * 128 + w * 32;

    const bf16* Qh = Q + (size_t)(b * 2048) * 256 + hd * 32;   // natural layout
    size_t kbase0 = (size_t)(b * 2048) * 256 + hd * 32;        // K natural base
    // Vt blocked [b][nb][c][64]; this head's c-rows start at hd*32
    const bf16* Vtb = Vt + (size_t)(b * 32) * 256 * 64;

    bf16x8 qf[2];
#pragma unroll
    for (int h = 0; h < 2; ++h)
        qf[h] = *reinterpret_cast<const bf16x8*>(
            Qh + (size_t)(qrow0 + h * 16 + cc) * 256 + g * 8);

    int kp0 = 8 * (cc >> 2) + (cc & 3);
    int kperm[4], koff[4];
#pragma unroll
    for (int r = 0; r < 4; ++r) {
        kperm[r] = 32 * (r >> 1) + 4 * (r & 1) + kp0;
        int fr = ((kperm[r] >> 1) ^ (kperm[r] >> 3)) & 3;
        koff[r] = kperm[r] * 32 + ((g ^ fr) * 8);
    }

    int krow = w * 16 + (lane >> 2);              // K row this lane stages
    int fkr = ((krow >> 1) ^ (krow >> 3)) & 3;
    int kcol = (((lane & 3) ^ fkr)) * 8;          // swizzled source chunk
    int dv = w * 8 + (lane >> 3);                 // V c-sub-row this lane stages
    int vcol = ((lane & 7) ^ (lane >> 3)) * 8;    // swizzled src col (elems)

    float lsum[2] = {0.f, 0.f};
    f32x4 oA[2] = {}, oB[2] = {};

#define STAGE(t, buf)                                                           \
    do {                                                                        \
        int kb_ = kv0 + (t) * 64;                                               \
        const bf16* kg_ = K + kbase0 + (size_t)(kb_ + krow) * 256 + kcol;       \
        GLL16(kg_, &sK[buf][w * 512]);                                          \
        const bf16* vg_ = Vtb + ((size_t)(kb_ >> 6) * 256 + hd * 32 + dv) * 64  \
                          + vcol;                                               \
        GLL16(vg_, &sV[buf][w * 512]);                                          \
    } while (0)

    // prologue: two tiles in flight
    STAGE(0, 0);
    STAGE(1, 1);

    for (int kt = 0; kt < 16; ++kt) {
        int cur = kt & 3;
        if (kt + 2 < 16) {
            STAGE(kt + 2, (kt + 2) & 3);
            // tile kt's loads (oldest 2 of 6 outstanding) complete
            asm volatile("s_waitcnt vmcnt(4)" ::: "memory");
        } else {
            // tail: nothing new issued; drain everything for tile kt
            asm volatile("s_waitcnt vmcnt(0)" ::: "memory");
        }
        __builtin_amdgcn_s_barrier();
        __builtin_amdgcn_sched_barrier(0);   // pin ds_reads after the barrier

        bf16x8 kf[4], vf[4];
#pragma unroll
        for (int r = 0; r < 4; ++r)
            kf[r] = *reinterpret_cast<const bf16x8*>(&sK[cur][koff[r]]);
#pragma unroll
        for (int dt = 0; dt < 2; ++dt)
#pragma unroll
            for (int kk = 0; kk < 2; ++kk) {
                int colp = (kk * 4 + g) ^ (cc & 7);
                vf[dt * 2 + kk] = *reinterpret_cast<const bf16x8*>(
                    &sV[cur][(dt * 16 + cc) * 64 + colp * 8]);
            }

#pragma unroll
        for (int h = 0; h < 2; ++h) {
            f32x4 z = {};
            f32x4 s[4];
            __builtin_amdgcn_s_setprio(1);
#pragma unroll
            for (int r = 0; r < 4; ++r) s[r] = MFMA(kf[r], qf[h], z);
            __builtin_amdgcn_s_setprio(0);

#pragma unroll
            for (int r = 0; r < 4; ++r)
#pragma unroll
                for (int j = 0; j < 4; ++j) s[r][j] = fexp2(s[r][j]);
            float t0 = (s[0][0] + s[0][1]) + (s[0][2] + s[0][3]);
            float t1 = (s[1][0] + s[1][1]) + (s[1][2] + s[1][3]);
            float t2 = (s[2][0] + s[2][1]) + (s[2][2] + s[2][3]);
            float t3 = (s[3][0] + s[3][1]) + (s[3][2] + s[3][3]);
            lsum[h] += (t0 + t1) + (t2 + t3);

            bf16x8 pb[2];
#pragma unroll
            for (int kk = 0; kk < 2; ++kk)
#pragma unroll
                for (int e = 0; e < 8; ++e)
                    pb[kk][e] = (bf16)s[2 * kk + (e >> 2)][e & 3];

            __builtin_amdgcn_s_setprio(1);
            oA[h] = MFMA(vf[0], pb[0], oA[h]);
            oA[h] = MFMA(vf[1], pb[1], oA[h]);
            oB[h] = MFMA(vf[2], pb[0], oB[h]);
            oB[h] = MFMA(vf[3], pb[1], oB[h]);
            __builtin_amdgcn_s_setprio(0);
        }
    }
#undef STAGE

#pragma unroll
    for (int h = 0; h < 2; ++h) {
        lsum[h] += __shfl_xor(lsum[h], 16);
        lsum[h] += __shfl_xor(lsum[h], 32);

        bf16* Pp = P + (size_t)split * 2097152 +
                   ((size_t)b * 2048 + qrow0 + h * 16 + cc) * 256 + hd * 32;
        bf16x4 w0, w1;
#pragma unroll
        for (int j = 0; j < 4; ++j) {
            w0[j] = (bf16)oA[h][j];
            w1[j] = (bf16)oB[h][j];
        }
        *reinterpret_cast<bf16x4*>(Pp + 4 * g) = w0;
        *reinterpret_cast<bf16x4*>(Pp + 16 + 4 * g) = w1;
        if (g == 0)
            Lf[(size_t)split * 65536 + (size_t)bh * 2048 + qrow0 + h * 16 + cc] = lsum[h];
    }
}

// ---------------- kernel 3: combine partials + output projection + bias -------
__global__ __launch_bounds__(64) void k_out(const bf16* __restrict__ P,
                                            const float* __restrict__ Lf,
                                            const bf16* __restrict__ WoT,
                                            const float* __restrict__ bo,
                                            float* __restrict__ out) {
    int m = blockIdx.x, nb = blockIdx.y;
    int l = threadIdx.x;
    int cc = l & 15, g = l >> 4;
    int arow = m * 16 + cc;
    int b = arow >> 11, n = arow & 2047;

    f32x4 acc[4] = {};
#pragma unroll
    for (int kc = 0; kc < 8; ++kc) {   // kc == head index for this 32-col chunk
        float l0 = Lf[(size_t)(b * 8 + kc) * 2048 + n];
        float l1 = Lf[65536 + (size_t)(b * 8 + kc) * 2048 + n];
        float inv = 1.0f / (l0 + l1);
        bf16x8 p0 = *reinterpret_cast<const bf16x8*>(
            P + (size_t)arow * 256 + kc * 32 + g * 8);
        bf16x8 p1 = *reinterpret_cast<const bf16x8*>(
            P + 2097152 + (size_t)arow * 256 + kc * 32 + g * 8);
        bf16x8 af;
#pragma unroll
        for (int e = 0; e < 8; ++e)
            af[e] = (bf16)(((float)p0[e] + (float)p1[e]) * inv);
#pragma unroll
        for (int ct = 0; ct < 4; ++ct) {
            bf16x8 bf = *reinterpret_cast<const bf16x8*>(
                WoT + (size_t)(nb * 64 + ct * 16 + cc) * 256 + kc * 32 + g * 8);
            acc[ct] = MFMA(af, bf, acc[ct]);
        }
    }
#pragma unroll
    for (int ct = 0; ct < 4; ++ct) {
        int col = nb * 64 + ct * 16 + cc;
        float bias = bo[col];
#pragma unroll
        for (int j = 0; j < 4; ++j) {
            int row = m * 16 + 4 * g + j;
            out[(size_t)row * 256 + col] = acc[ct][j] + bias;
        }
    }
}

extern "C" void kernel_launch(void* const* d_in, const int* in_sizes, int n_in,
                              void* d_out, int out_size, void* d_ws, size_t ws_size,
                              hipStream_t stream) {
    const float* c2 = (const float*)d_in[0];
    const float* c1 = (const float*)d_in[1];
    const float* Wq = (const float*)d_in[2];
    const float* Wk = (const float*)d_in[3];
    const float* Wv = (const float*)d_in[4];
    const float* Wo = (const float*)d_in[5];
    const float* bo = (const float*)d_in[6];
    float* out = (float*)d_out;

    bf16* ws = (bf16*)d_ws;
    bf16* wts = ws;
    bf16* Q = ws + OFF_Q;
    bf16* Vt = ws + OFF_VT;
    bf16* P = ws + OFF_P;
    float* Lf = (float*)(ws + OFF_L);

    k_wt<<<dim3(4, 4, 4), 256, 0, stream>>>(Wq, Wk, Wv, Wo, wts);
    k_proj<<<dim3(256, 3), 256, 0, stream>>>(c1, c2, wts, Q);
    k_attn<<<dim3(1024), 256, 0, stream>>>(Q, ws + OFF_K, Vt, P, Lf);
    k_out<<<dim3(512, 4), 64, 0, stream>>>(P, Lf, wts + 3 * 65536, bo, out);
}